// Round 11
// baseline (1130.277 us; speedup 1.0000x reference)
//
#include <hip/hip_runtime.h>
#include <math.h>

#define TPB 256
#define BSH 8                  // 256 nodes per bucket (TPB must equal 1<<BSH)
#define BMAX 512               // max buckets (N <= 131072)
#define EPB 4096               // edges per block in hist/bucket passes

// ---------------- CSR build (bucketed, no global random atomics) ----------------

__global__ __launch_bounds__(TPB) void k_hist(const int* __restrict__ dst,
                                              int* __restrict__ bucketCnt,
                                              int nE, int nbuck) {
  __shared__ int h[BMAX];
  for (int i = threadIdx.x; i < BMAX; i += TPB) h[i] = 0;
  __syncthreads();
  int base = blockIdx.x * EPB;
  for (int i = threadIdx.x; i < EPB; i += TPB) {
    int e = base + i;
    if (e < nE) atomicAdd(&h[dst[e] >> BSH], 1);
  }
  __syncthreads();
  for (int i = threadIdx.x; i < nbuck; i += TPB)
    if (h[i]) atomicAdd(&bucketCnt[i], h[i]);
}

__global__ __launch_bounds__(BMAX) void k_bscan(const int* __restrict__ bucketCnt,
                                                int* __restrict__ bOff,
                                                int* __restrict__ gCur,
                                                int* __restrict__ rowPtr,
                                                int nbuck, int n, int nE) {
  __shared__ int sd[BMAX];
  int t = threadIdx.x;
  int v = (t < nbuck) ? bucketCnt[t] : 0;
  sd[t] = v;
  __syncthreads();
  for (int off = 1; off < BMAX; off <<= 1) {
    int add = (t >= off) ? sd[t - off] : 0;
    __syncthreads();
    sd[t] += add;
    __syncthreads();
  }
  if (t < nbuck) {
    bOff[t + 1] = sd[t];
    gCur[t] = sd[t] - v;     // exclusive prefix
  }
  if (t == 0) { bOff[0] = 0; rowPtr[n] = nE; }
}

__global__ __launch_bounds__(TPB) void k_bucket(const int* __restrict__ src,
                                                const int* __restrict__ dst,
                                                int* __restrict__ gCur,
                                                int* __restrict__ pairBuf,
                                                int nE, int nbuck) {
  __shared__ int   hist[BMAX];
  __shared__ int   baseL[BMAX];
  __shared__ int   sp[EPB];
  __shared__ short sbk[EPB];
  for (int i = threadIdx.x; i < BMAX; i += TPB) hist[i] = 0;
  __syncthreads();
  int cb = blockIdx.x * EPB;
  for (int i = threadIdx.x; i < EPB; i += TPB) {
    int e = cb + i;
    if (e < nE) {
      int s = src[e], d = dst[e];
      int b = d >> BSH;
      sp[i]  = s | ((d & ((1 << BSH) - 1)) << 20);
      sbk[i] = (short)b;
      atomicAdd(&hist[b], 1);
    } else sbk[i] = -1;
  }
  __syncthreads();
  for (int i = threadIdx.x; i < nbuck; i += TPB)
    baseL[i] = hist[i] ? atomicAdd(&gCur[i], hist[i]) : 0;
  __syncthreads();
  for (int i = threadIdx.x; i < BMAX; i += TPB) hist[i] = 0;  // reuse as cursor
  __syncthreads();
  for (int i = threadIdx.x; i < EPB; i += TPB) {
    int b = sbk[i];
    if (b >= 0) {
      int r = atomicAdd(&hist[b], 1);
      pairBuf[baseL[b] + r] = sp[i];
    }
  }
}

__global__ __launch_bounds__(TPB) void k_final(const int* __restrict__ pairBuf,
                                               const int* __restrict__ bOff,
                                               int* __restrict__ rowPtr,
                                               int* __restrict__ col,
                                               float* __restrict__ dinv,
                                               int n) {
  __shared__ int h[TPB];
  __shared__ int ex[TPB];
  int t = threadIdx.x;
  int b = blockIdx.x;
  int p0 = bOff[b], p1 = bOff[b + 1];
  h[t] = 0;
  __syncthreads();
  for (int i = p0 + t; i < p1; i += TPB)
    atomicAdd(&h[pairBuf[i] >> 20], 1);
  __syncthreads();
  int v = h[t];
  ex[t] = v;
  __syncthreads();
  for (int off = 1; off < TPB; off <<= 1) {
    int add = (t >= off) ? ex[t - off] : 0;
    __syncthreads();
    ex[t] += add;
    __syncthreads();
  }
  int excl = ex[t] - v;
  int node = (b << BSH) + t;
  if (node < n) {
    rowPtr[node] = p0 + excl;
    dinv[node]   = rsqrtf((float)(v + 1));  // +1 self loop
  }
  __syncthreads();
  h[t] = excl;  // reuse as per-local-node cursor
  __syncthreads();
  for (int i = p0 + t; i < p1; i += TPB) {
    int p = pairBuf[i];
    int r = atomicAdd(&h[p >> 20], 1);
    col[p0 + r] = p & 0xFFFFF;
  }
}

// ---------------- per-layer kernels ----------------
// Hidden-feature layout: 4-SLICE — buf[s][node][16ch], s<4, offset =
// s*N16 + node*16 + c (N16 = N*16). Slice row = 64B = exactly one cache
// line. slice = blockIdx&3 with round-robin blockIdx%8->XCD dispatch pins
// each 6.4MB slice to 2 XCDs' L2s (mechanism verified round 6), keeping
// full-line gathers (K=8's 32B sub-line requests were the round-6/7 bound).

// HWS[s][n][c] = (act(H[n]) @ W)[c] * dinv[n]
__global__ __launch_bounds__(TPB, 4) void k_gemm(const float* __restrict__ H,
                                                 const float* __restrict__ W,
                                                 const float* __restrict__ dinv,
                                                 float* __restrict__ HWS,
                                                 int relu, int denseIn,
                                                 int rows, int N16) {
  __shared__ float Wl[64 * 64];     // [k][c]
  __shared__ float Hl[64][68];      // [r][k], padded
  const int tid = threadIdx.x;
  const int c0 = (tid & 15) * 4;
  const int r0 = (tid >> 4) * 4;
  const int row0 = blockIdx.x * 64;

  for (int i = tid; i < 64 * 16; i += TPB)
    ((float4*)Wl)[i] = ((const float4*)W)[i];

  if (denseIn) {
    for (int i = tid; i < 64 * 16; i += TPB) {
      int r = i >> 4, q = i & 15;
      int gr = row0 + r;
      float4 v = make_float4(0.f, 0.f, 0.f, 0.f);
      if (gr < rows) v = ((const float4*)(H + (size_t)gr * 64))[q];
      if (relu) {
        v.x = fmaxf(v.x, 0.f); v.y = fmaxf(v.y, 0.f);
        v.z = fmaxf(v.z, 0.f); v.w = fmaxf(v.w, 0.f);
      }
      *(float4*)&Hl[r][q * 4] = v;
    }
  } else {
    // sliced read: q=i&15 -> slice q>>2, within-slice float4 (q&3)
    for (int i = tid; i < 64 * 16; i += TPB) {
      int r = i >> 4, q = i & 15;
      int sl = q >> 2, off = (q & 3) * 4;
      int gr = row0 + r;
      float4 v = make_float4(0.f, 0.f, 0.f, 0.f);
      if (gr < rows)
        v = *(const float4*)&H[(size_t)sl * N16 + (size_t)gr * 16 + off];
      if (relu) {
        v.x = fmaxf(v.x, 0.f); v.y = fmaxf(v.y, 0.f);
        v.z = fmaxf(v.z, 0.f); v.w = fmaxf(v.w, 0.f);
      }
      *(float4*)&Hl[r][q * 4] = v;
    }
  }
  __syncthreads();

  float acc[4][4] = {{0.f,0.f,0.f,0.f},{0.f,0.f,0.f,0.f},
                     {0.f,0.f,0.f,0.f},{0.f,0.f,0.f,0.f}};
#pragma unroll 4
  for (int k = 0; k < 64; ++k) {
    float4 w = *(const float4*)&Wl[k * 64 + c0];
    float h0 = Hl[r0 + 0][k];
    float h1 = Hl[r0 + 1][k];
    float h2 = Hl[r0 + 2][k];
    float h3 = Hl[r0 + 3][k];
    acc[0][0] = fmaf(h0, w.x, acc[0][0]); acc[0][1] = fmaf(h0, w.y, acc[0][1]);
    acc[0][2] = fmaf(h0, w.z, acc[0][2]); acc[0][3] = fmaf(h0, w.w, acc[0][3]);
    acc[1][0] = fmaf(h1, w.x, acc[1][0]); acc[1][1] = fmaf(h1, w.y, acc[1][1]);
    acc[1][2] = fmaf(h1, w.z, acc[1][2]); acc[1][3] = fmaf(h1, w.w, acc[1][3]);
    acc[2][0] = fmaf(h2, w.x, acc[2][0]); acc[2][1] = fmaf(h2, w.y, acc[2][1]);
    acc[2][2] = fmaf(h2, w.z, acc[2][2]); acc[2][3] = fmaf(h2, w.w, acc[2][3]);
    acc[3][0] = fmaf(h3, w.x, acc[3][0]); acc[3][1] = fmaf(h3, w.y, acc[3][1]);
    acc[3][2] = fmaf(h3, w.z, acc[3][2]); acc[3][3] = fmaf(h3, w.w, acc[3][3]);
  }

  const int sOut = c0 >> 4;          // output slice
  const int coff = c0 & 15;          // offset within slice row
#pragma unroll
  for (int i = 0; i < 4; ++i) {
    int gr = row0 + r0 + i;
    if (gr < rows) {
      float s = dinv[gr];
      float4 o = make_float4(acc[i][0] * s, acc[i][1] * s,
                             acc[i][2] * s, acc[i][3] * s);
      *(float4*)&HWS[(size_t)sOut * N16 + (size_t)gr * 16 + coff] = o;
    }
  }
}

// 4-slice aggregate: OUT[s][n][c] = dinv[n]*(HWS[s][n][c] + sum_e HWS[s][col[e]][c]) + bias[s*16+c]
// Wave per (node, slice). lane = (edge-slot es=lane>>2, quad q=lane&3).
// One dwordx4 instruction gathers 16 edges x 64B (full lines, 1KB/instr).
// All __shfl in wave-uniform control flow (round-4 lesson).
__global__ __launch_bounds__(TPB) void k_scat4(const float* __restrict__ HWS,
                                               const int* __restrict__ rowPtr,
                                               const int* __restrict__ col,
                                               const float* __restrict__ dinv,
                                               const float* __restrict__ bias,
                                               float* __restrict__ OUT,
                                               int n, int N16) {
  const int slice = blockIdx.x & 3;
  const int nb    = blockIdx.x >> 2;
  const int wv    = threadIdx.x >> 6;
  const int node  = nb * 4 + wv;
  if (node >= n) return;
  const int lane = threadIdx.x & 63;
  const int es = lane >> 2;   // edge slot 0..15
  const int q  = lane & 3;    // float4 quadrant of the 64B slice row
  const float* __restrict__ tab = HWS + (size_t)slice * N16;

  float4 acc = make_float4(0.f, 0.f, 0.f, 0.f);
  if (es == 0)  // self loop counted once
    acc = *(const float4*)&tab[(size_t)node * 16 + q * 4];

  const int e0 = rowPtr[node];
  const int deg = rowPtr[node + 1] - e0;

  for (int base = 0; base < deg; base += 64) {
    int m = deg - base; if (m > 64) m = 64;
    int idxv = (lane < m) ? col[e0 + base + lane] : 0;
    int j = 0;
    // uniform trip count: all 64 lanes active at every __shfl
    for (; j + 16 <= m; j += 16) {
      int s = __shfl(idxv, j + es, 64);
      float4 v = *(const float4*)&tab[(size_t)s * 16 + q * 4];
      acc.x += v.x; acc.y += v.y; acc.z += v.z; acc.w += v.w;
    }
    for (; j < m; j += 16) {
      int jj = j + es;
      int jc = (jj < m) ? jj : (m - 1);     // clamp: source lane always < m
      int s = __shfl(idxv, jc, 64);         // executed by ALL lanes (uniform)
      if (jj < m) {                         // only the gather is predicated
        float4 v = *(const float4*)&tab[(size_t)s * 16 + q * 4];
        acc.x += v.x; acc.y += v.y; acc.z += v.z; acc.w += v.w;
      }
    }
  }

  // reduce across the 16 edge slots (lanes q, q+4, ..., q+60)
#pragma unroll
  for (int off = 4; off < 64; off <<= 1) {
    acc.x += __shfl_xor(acc.x, off, 64);
    acc.y += __shfl_xor(acc.y, off, 64);
    acc.z += __shfl_xor(acc.z, off, 64);
    acc.w += __shfl_xor(acc.w, off, 64);
  }

  if (es == 0) {
    float s = dinv[node];
    float4 b4 = *(const float4*)&bias[slice * 16 + q * 4];
    float4 o = make_float4(acc.x * s + b4.x, acc.y * s + b4.y,
                           acc.z * s + b4.z, acc.w * s + b4.w);
    *(float4*)&OUT[(size_t)slice * N16 + (size_t)node * 16 + q * 4] = o;
  }
}

// hws1[n] = (relu(H[n]) . Wo) * dinv[n]  — H 4-sliced
__global__ __launch_bounds__(TPB) void k_fdot(const float* __restrict__ H,
                                              const float* __restrict__ Wo,
                                              const float* __restrict__ dinv,
                                              float* __restrict__ hws1,
                                              int n, int N16) {
  int i = blockIdx.x * TPB + threadIdx.x;
  if (i >= n) return;
  float acc = 0.f;
#pragma unroll
  for (int s = 0; s < 4; ++s) {
#pragma unroll
    for (int t = 0; t < 4; ++t) {
      float4 v = *(const float4*)&H[(size_t)s * N16 + (size_t)i * 16 + t * 4];
      acc += fmaxf(v.x, 0.f) * Wo[s * 16 + t * 4 + 0];
      acc += fmaxf(v.y, 0.f) * Wo[s * 16 + t * 4 + 1];
      acc += fmaxf(v.z, 0.f) * Wo[s * 16 + t * 4 + 2];
      acc += fmaxf(v.w, 0.f) * Wo[s * 16 + t * 4 + 3];
    }
  }
  hws1[i] = acc * dinv[i];
}

__global__ __launch_bounds__(TPB) void k_fscat(const float* __restrict__ hws1,
                                               const int* __restrict__ rowPtr,
                                               const int* __restrict__ col,
                                               const float* __restrict__ dinv,
                                               const float* __restrict__ bo,
                                               float* __restrict__ out, int n) {
  int i = blockIdx.x * TPB + threadIdx.x;
  if (i >= n) return;
  float a0 = hws1[i], a1 = 0.f, a2 = 0.f, a3 = 0.f;
  int e0 = rowPtr[i], e1 = rowPtr[i + 1];
  int e = e0;
  for (; e + 4 <= e1; e += 4) {
    a0 += hws1[col[e]];
    a1 += hws1[col[e + 1]];
    a2 += hws1[col[e + 2]];
    a3 += hws1[col[e + 3]];
  }
  for (; e < e1; ++e) a0 += hws1[col[e]];
  out[i] = dinv[i] * ((a0 + a1) + (a2 + a3)) + bo[0];
}

// ---------------- launch ----------------

extern "C" void kernel_launch(void* const* d_in, const int* in_sizes, int n_in,
                              void* d_out, int out_size, void* d_ws, size_t ws_size,
                              hipStream_t stream) {
  const float* x   = (const float*)d_in[0];
  const int*   ei  = (const int*)d_in[1];
  const float* W_i = (const float*)d_in[2];
  const float* b_i = (const float*)d_in[3];
  const float* W_h = (const float*)d_in[4];
  const float* b_h = (const float*)d_in[5];
  const float* W_o = (const float*)d_in[6];
  const float* b_o = (const float*)d_in[7];

  const int N = in_sizes[0] / 64;   // 100000
  const int E = in_sizes[1] / 2;    // 2000000
  const int N16 = N * 16;
  const int* srcArr = ei;           // edge_index[0]
  const int* dstArr = ei + E;       // edge_index[1]
  const int nbuck = (N + (1 << BSH) - 1) >> BSH;   // 391

  char* w = (char*)d_ws;
  auto take = [&](size_t bytes) -> char* {
    char* p = w;
    w += (bytes + 255) & ~(size_t)255;
    return p;
  };
  int*   rowPtr    = (int*)take((size_t)(N + 1) * 4);
  int*   col       = (int*)take((size_t)E * 4);
  float* dinv      = (float*)take((size_t)N * 4);
  int*   bucketCnt = (int*)take((size_t)BMAX * 4);
  int*   bOff      = (int*)take((size_t)(BMAX + 1) * 4);
  int*   gCur      = (int*)take((size_t)BMAX * 4);
  float* bufH      = (float*)take((size_t)N * 64 * 4);
  float* bufS      = (float*)take((size_t)N * 64 * 4);
  float* hws1      = (float*)take((size_t)N * 4);
  int*   pairBuf   = (int*)bufS;   // alias: bufS unused during CSR build
  (void)ws_size; (void)n_in; (void)out_size;

  const int nbN    = (N + TPB - 1) / TPB;
  const int nbEd   = (E + EPB - 1) / EPB;
  const int nbGemm = (N + 63) / 64;
  const int nbScat = 4 * ((N + 3) / 4);   // blockIdx&3 = slice, 4 nodes/block

  // CSR build + dinv
  hipMemsetAsync(bucketCnt, 0, (size_t)BMAX * 4, stream);
  k_hist  <<<nbEd, TPB, 0, stream>>>(dstArr, bucketCnt, E, nbuck);
  k_bscan <<<1, BMAX, 0, stream>>>(bucketCnt, bOff, gCur, rowPtr, nbuck, N, E);
  k_bucket<<<nbEd, TPB, 0, stream>>>(srcArr, dstArr, gCur, pairBuf, E, nbuck);
  k_final <<<nbuck, TPB, 0, stream>>>(pairBuf, bOff, rowPtr, col, dinv, N);

  // layer 0: x (dense) -> bufS (sliced) -> bufH (sliced)
  k_gemm <<<nbGemm, TPB, 0, stream>>>(x, W_i, dinv, bufS, 0, 1, N, N16);
  k_scat4<<<nbScat, TPB, 0, stream>>>(bufS, rowPtr, col, dinv, b_i, bufH, N, N16);

  // 6 hidden layers (sliced layout throughout)
  for (int l = 0; l < 6; ++l) {
    k_gemm <<<nbGemm, TPB, 0, stream>>>(bufH, W_h + (size_t)l * 64 * 64, dinv, bufS, 1, 0, N, N16);
    k_scat4<<<nbScat, TPB, 0, stream>>>(bufS, rowPtr, col, dinv, b_h + (size_t)l * 64, bufH, N, N16);
  }

  // output layer: 64 -> 1
  k_fdot <<<nbN, TPB, 0, stream>>>(bufH, W_o, dinv, hws1, N, N16);
  k_fscat<<<nbN, TPB, 0, stream>>>(hws1, rowPtr, col, dinv, b_o, (float*)d_out, N);
}

// Round 12
// 857.236 us; speedup vs baseline: 1.3185x; 1.3185x over previous
//
#include <hip/hip_runtime.h>
#include <math.h>

#define TPB 256
#define BSH 5                  // 32 nodes per bucket
#define NPB (1 << BSH)
#define BMAX 4096              // max buckets (N <= 131072)
#define EPB 4096               // edges per block in hist/bucket passes
#define SMSK 0xFFFFF           // src mask in k_bucket packing
#define SORTN 1024             // bitonic capacity (bucket avg 640, max ~770)

// ---------------- edge bucketing (no global random atomics) ----------------

// pass A: coarse histogram of dst by bucket
__global__ __launch_bounds__(TPB) void k_hist(const int* __restrict__ dst,
                                              int* __restrict__ bucketCnt,
                                              int nE, int nbuck) {
  __shared__ int h[BMAX];
  for (int i = threadIdx.x; i < BMAX; i += TPB) h[i] = 0;
  __syncthreads();
  int base = blockIdx.x * EPB;
  for (int i = threadIdx.x; i < EPB; i += TPB) {
    int e = base + i;
    if (e < nE) atomicAdd(&h[dst[e] >> BSH], 1);
  }
  __syncthreads();
  for (int i = threadIdx.x; i < nbuck; i += TPB)
    if (h[i]) atomicAdd(&bucketCnt[i], h[i]);
}

// pass B: scan bucket counts (4 per thread, 1 block) -> bOff, gCur
__global__ __launch_bounds__(1024) void k_bscan(const int* __restrict__ bucketCnt,
                                                int* __restrict__ bOff,
                                                int* __restrict__ gCur,
                                                int nbuck) {
  __shared__ int sd[1024];
  int t = threadIdx.x;
  int i0 = 4 * t;
  int v0 = (i0     < nbuck) ? bucketCnt[i0]     : 0;
  int v1 = (i0 + 1 < nbuck) ? bucketCnt[i0 + 1] : 0;
  int v2 = (i0 + 2 < nbuck) ? bucketCnt[i0 + 2] : 0;
  int v3 = (i0 + 3 < nbuck) ? bucketCnt[i0 + 3] : 0;
  int s = v0 + v1 + v2 + v3;
  sd[t] = s;
  __syncthreads();
  for (int off = 1; off < 1024; off <<= 1) {
    int add = (t >= off) ? sd[t - off] : 0;
    __syncthreads();
    sd[t] += add;
    __syncthreads();
  }
  int base = sd[t] - s;   // exclusive prefix
  if (i0     < nbuck) { gCur[i0]     = base;                bOff[i0 + 1] = base + v0; }
  if (i0 + 1 < nbuck) { gCur[i0 + 1] = base + v0;           bOff[i0 + 2] = base + v0 + v1; }
  if (i0 + 2 < nbuck) { gCur[i0 + 2] = base + v0 + v1;      bOff[i0 + 3] = base + v0 + v1 + v2; }
  if (i0 + 3 < nbuck) { gCur[i0 + 3] = base + v0 + v1 + v2; bOff[i0 + 4] = base + v0 + v1 + v2 + v3; }
  if (t == 0) bOff[0] = 0;
}

// pass C: scatter packed (src | dlocal<<20) into bucket-sorted pairBuf
__global__ __launch_bounds__(TPB) void k_bucket(const int* __restrict__ src,
                                                const int* __restrict__ dst,
                                                int* __restrict__ gCur,
                                                int* __restrict__ pairBuf,
                                                int nE, int nbuck) {
  __shared__ int   hist[BMAX];
  __shared__ int   baseL[BMAX];
  __shared__ int   sp[EPB];
  __shared__ short sbk[EPB];
  for (int i = threadIdx.x; i < BMAX; i += TPB) hist[i] = 0;
  __syncthreads();
  int cb = blockIdx.x * EPB;
  for (int i = threadIdx.x; i < EPB; i += TPB) {
    int e = cb + i;
    if (e < nE) {
      int s = src[e], d = dst[e];
      int b = d >> BSH;
      sp[i]  = s | ((d & (NPB - 1)) << 20);
      sbk[i] = (short)b;
      atomicAdd(&hist[b], 1);
    } else sbk[i] = -1;
  }
  __syncthreads();
  for (int i = threadIdx.x; i < nbuck; i += TPB)
    baseL[i] = hist[i] ? atomicAdd(&gCur[i], hist[i]) : 0;
  __syncthreads();
  for (int i = threadIdx.x; i < BMAX; i += TPB) hist[i] = 0;  // reuse as cursor
  __syncthreads();
  for (int i = threadIdx.x; i < EPB; i += TPB) {
    int b = sbk[i];
    if (b >= 0) {
      int r = atomicAdd(&hist[b], 1);
      pairBuf[baseL[b] + r] = sp[i];
    }
  }
}

// pass D: per-bucket degree histogram -> dinv (OLD packing: dl = p>>20)
__global__ __launch_bounds__(TPB) void k_deg(const int* __restrict__ pairBuf,
                                             const int* __restrict__ bOff,
                                             float* __restrict__ dinv, int n) {
  __shared__ int h[NPB];
  int t = threadIdx.x;
  int b = blockIdx.x;
  if (t < NPB) h[t] = 0;
  __syncthreads();
  int p0 = bOff[b], p1 = bOff[b + 1];
  for (int i = p0 + t; i < p1; i += TPB)
    atomicAdd(&h[pairBuf[i] >> 20], 1);
  __syncthreads();
  if (t < NPB) {
    int node = (b << BSH) + t;
    if (node < n) dinv[node] = rsqrtf((float)(h[t] + 1));  // +1 self loop
  }
}

// pass E: per-bucket REPACK to (src<<5 | dlocal) and bitonic sort ascending
// (src-major). Sorting is perf-only (aligns all blocks' gather streams into a
// common low->high sweep so the live ~1-2MB window is L2-resident everywhere);
// repack is REQUIRED (k_swp/k_fsc decode the new packing).
__global__ __launch_bounds__(TPB) void k_sort(int* __restrict__ pairBuf,
                                              const int* __restrict__ bOff) {
  __shared__ int sp[SORTN];
  const int b = blockIdx.x, t = threadIdx.x;
  const int p0 = bOff[b];
  const int sz = bOff[b + 1] - p0;
  if (sz > SORTN) {   // fallback: repack only (correct, just unsorted)
    for (int i = t; i < sz; i += TPB) {
      int p = pairBuf[p0 + i];
      pairBuf[p0 + i] = ((p & SMSK) << BSH) | (p >> 20);
    }
    return;
  }
  for (int i = t; i < SORTN; i += TPB) {
    int v = 0x7FFFFFFF;
    if (i < sz) { int p = pairBuf[p0 + i]; v = ((p & SMSK) << BSH) | (p >> 20); }
    sp[i] = v;
  }
  __syncthreads();
  for (int k = 2; k <= SORTN; k <<= 1) {
    for (int j = k >> 1; j > 0; j >>= 1) {
      for (int i = t; i < SORTN; i += TPB) {
        int ixj = i ^ j;
        if (ixj > i) {
          int x = sp[i], y = sp[ixj];
          bool up = ((i & k) == 0);
          if ((x > y) == up) { sp[i] = y; sp[ixj] = x; }
        }
      }
      __syncthreads();
    }
  }
  for (int i = t; i < sz; i += TPB) pairBuf[p0 + i] = sp[i];
}

// ---------------- per-layer kernels (dense N x 64 row-major) ----------------

// HWS[n][c] = (act(H[n]) @ W)[c] * dinv[n]
__global__ __launch_bounds__(TPB, 4) void k_gemm(const float* __restrict__ H,
                                                 const float* __restrict__ W,
                                                 const float* __restrict__ dinv,
                                                 float* __restrict__ HWS,
                                                 int relu, int rows) {
  __shared__ float Wl[64 * 64];     // [k][c]
  __shared__ float Hl[64][68];      // [r][k], padded
  const int tid = threadIdx.x;
  const int c0 = (tid & 15) * 4;
  const int r0 = (tid >> 4) * 4;
  const int row0 = blockIdx.x * 64;

  for (int i = tid; i < 64 * 16; i += TPB)
    ((float4*)Wl)[i] = ((const float4*)W)[i];

  for (int i = tid; i < 64 * 16; i += TPB) {
    int r = i >> 4, q = i & 15;
    int gr = row0 + r;
    float4 v = make_float4(0.f, 0.f, 0.f, 0.f);
    if (gr < rows) v = ((const float4*)(H + (size_t)gr * 64))[q];
    if (relu) {
      v.x = fmaxf(v.x, 0.f); v.y = fmaxf(v.y, 0.f);
      v.z = fmaxf(v.z, 0.f); v.w = fmaxf(v.w, 0.f);
    }
    *(float4*)&Hl[r][q * 4] = v;
  }
  __syncthreads();

  float acc[4][4] = {{0.f,0.f,0.f,0.f},{0.f,0.f,0.f,0.f},
                     {0.f,0.f,0.f,0.f},{0.f,0.f,0.f,0.f}};
#pragma unroll 4
  for (int k = 0; k < 64; ++k) {
    float4 w = *(const float4*)&Wl[k * 64 + c0];
    float h0 = Hl[r0 + 0][k];
    float h1 = Hl[r0 + 1][k];
    float h2 = Hl[r0 + 2][k];
    float h3 = Hl[r0 + 3][k];
    acc[0][0] = fmaf(h0, w.x, acc[0][0]); acc[0][1] = fmaf(h0, w.y, acc[0][1]);
    acc[0][2] = fmaf(h0, w.z, acc[0][2]); acc[0][3] = fmaf(h0, w.w, acc[0][3]);
    acc[1][0] = fmaf(h1, w.x, acc[1][0]); acc[1][1] = fmaf(h1, w.y, acc[1][1]);
    acc[1][2] = fmaf(h1, w.z, acc[1][2]); acc[1][3] = fmaf(h1, w.w, acc[1][3]);
    acc[2][0] = fmaf(h2, w.x, acc[2][0]); acc[2][1] = fmaf(h2, w.y, acc[2][1]);
    acc[2][2] = fmaf(h2, w.z, acc[2][2]); acc[2][3] = fmaf(h2, w.w, acc[2][3]);
    acc[3][0] = fmaf(h3, w.x, acc[3][0]); acc[3][1] = fmaf(h3, w.y, acc[3][1]);
    acc[3][2] = fmaf(h3, w.z, acc[3][2]); acc[3][3] = fmaf(h3, w.w, acc[3][3]);
  }

#pragma unroll
  for (int i = 0; i < 4; ++i) {
    int gr = row0 + r0 + i;
    if (gr < rows) {
      float s = dinv[gr];
      float4 o = make_float4(acc[i][0] * s, acc[i][1] * s,
                             acc[i][2] * s, acc[i][3] * s);
      *(float4*)&HWS[(size_t)gr * 64 + c0] = o;
    }
  }
}

// Sweep aggregation: ONE WAVE per block, block = 32-node bucket, PRIVATE 8KB
// LDS accumulator -> non-atomic read-add-write (single wave: LDS ops are in
// program order; no atomics, no barriers). lane = channel: gather is one
// 256B coalesced instruction/edge; acc RMW is 64 consecutive floats (2-way
// bank aliasing = free). Edges src-sorted: all 3125 co-resident blocks sweep
// the 25.6MB table in phase -> live window ~1-2MB, L2-resident per XCD;
// leading-edge misses are quasi-sequential.
__global__ __launch_bounds__(64) void k_swp(const float* __restrict__ HWS,
                                            const int* __restrict__ pairBuf,
                                            const int* __restrict__ bOff,
                                            const float* __restrict__ dinv,
                                            const float* __restrict__ bias,
                                            float* __restrict__ OUT, int n) {
  __shared__ float acc[NPB * 64];   // 8KB, private to this block's single wave
  const int b = blockIdx.x;
  const int lane = threadIdx.x;     // 0..63 == channel
  const int node0 = b << BSH;
  const float4* __restrict__ tab4 = (const float4*)HWS;

  // init with self-loop rows (HWS already dinv-prescaled)
  for (int i = lane; i < NPB * 16; i += 64) {
    int dl = i >> 4, q = i & 15;
    int node = node0 + dl;
    float4 v = make_float4(0.f, 0.f, 0.f, 0.f);
    if (node < n) v = tab4[(size_t)node * 16 + q];
    *(float4*)&acc[(dl << 6) + q * 4] = v;
  }

  const int p0 = bOff[b], p1 = bOff[b + 1];
  for (int base = p0; base < p1; base += 64) {
    int m = p1 - base; if (m > 64) m = 64;
    int pv = (lane < m) ? pairBuf[base + lane] : 0;  // packed (src<<5)|dl
    int j = 0;
    // uniform trip counts: all 64 lanes active at every __shfl
    for (; j + 8 <= m; j += 8) {
      int pa = __shfl(pv, j    , 64);
      int pb = __shfl(pv, j + 1, 64);
      int pc = __shfl(pv, j + 2, 64);
      int pd = __shfl(pv, j + 3, 64);
      int pe = __shfl(pv, j + 4, 64);
      int pf = __shfl(pv, j + 5, 64);
      int pg = __shfl(pv, j + 6, 64);
      int ph = __shfl(pv, j + 7, 64);
      float va = HWS[(size_t)(pa >> BSH) * 64 + lane];
      float vb = HWS[(size_t)(pb >> BSH) * 64 + lane];
      float vc = HWS[(size_t)(pc >> BSH) * 64 + lane];
      float vd = HWS[(size_t)(pd >> BSH) * 64 + lane];
      float ve = HWS[(size_t)(pe >> BSH) * 64 + lane];
      float vf = HWS[(size_t)(pf >> BSH) * 64 + lane];
      float vg = HWS[(size_t)(pg >> BSH) * 64 + lane];
      float vh = HWS[(size_t)(ph >> BSH) * 64 + lane];
      acc[((pa & (NPB - 1)) << 6) + lane] += va;
      acc[((pb & (NPB - 1)) << 6) + lane] += vb;
      acc[((pc & (NPB - 1)) << 6) + lane] += vc;
      acc[((pd & (NPB - 1)) << 6) + lane] += vd;
      acc[((pe & (NPB - 1)) << 6) + lane] += ve;
      acc[((pf & (NPB - 1)) << 6) + lane] += vf;
      acc[((pg & (NPB - 1)) << 6) + lane] += vg;
      acc[((ph & (NPB - 1)) << 6) + lane] += vh;
    }
    for (; j < m; ++j) {
      int p = __shfl(pv, j, 64);
      acc[((p & (NPB - 1)) << 6) + lane] += HWS[(size_t)(p >> BSH) * 64 + lane];
    }
  }

  // epilogue: OUT[node][c] = dinv*acc + bias (coalesced)
  for (int i = lane; i < NPB * 16; i += 64) {
    int dl = i >> 4, q = i & 15;
    int node = node0 + dl;
    if (node < n) {
      float s = dinv[node];
      float4 a  = *(float4*)&acc[(dl << 6) + q * 4];
      float4 b4 = *(const float4*)&bias[q * 4];
      *(float4*)&OUT[(size_t)node * 64 + q * 4] =
          make_float4(a.x * s + b4.x, a.y * s + b4.y,
                      a.z * s + b4.z, a.w * s + b4.w);
    }
  }
}

// hws1[n] = (relu(H[n]) . Wo) * dinv[n]
__global__ __launch_bounds__(TPB) void k_fdot(const float* __restrict__ H,
                                              const float* __restrict__ Wo,
                                              const float* __restrict__ dinv,
                                              float* __restrict__ hws1, int n) {
  int i = blockIdx.x * TPB + threadIdx.x;
  if (i >= n) return;
  const float4* Hv = (const float4*)(H + (size_t)i * 64);
  float acc = 0.f;
#pragma unroll
  for (int q = 0; q < 16; ++q) {
    float4 v = Hv[q];
    acc += fmaxf(v.x, 0.f) * Wo[4 * q + 0];
    acc += fmaxf(v.y, 0.f) * Wo[4 * q + 1];
    acc += fmaxf(v.z, 0.f) * Wo[4 * q + 2];
    acc += fmaxf(v.w, 0.f) * Wo[4 * q + 3];
  }
  hws1[i] = acc * dinv[i];
}

// final 1-channel aggregation: 1 wave per bucket, per-bin shfl reduce into
// VGPRs (no atomics, no LDS). Edges in new packing (src<<5)|dl.
__global__ __launch_bounds__(64) void k_fsc(const float* __restrict__ hws1,
                                            const int* __restrict__ pairBuf,
                                            const int* __restrict__ bOff,
                                            const float* __restrict__ dinv,
                                            const float* __restrict__ bo,
                                            float* __restrict__ out, int n) {
  const int b = blockIdx.x;
  const int lane = threadIdx.x;
  const int node0 = b << BSH;
  float a[NPB];
#pragma unroll
  for (int d = 0; d < NPB; ++d) a[d] = 0.f;
  const int p0 = bOff[b], p1 = bOff[b + 1];
  for (int base = p0; base < p1; base += 64) {
    int m = p1 - base; if (m > 64) m = 64;
    int pv = (lane < m) ? pairBuf[base + lane] : 0;
    float v = (lane < m) ? hws1[pv >> BSH] : 0.f;
    int dl = pv & (NPB - 1);
#pragma unroll
    for (int d = 0; d < NPB; ++d) {
      float c = (dl == d) ? v : 0.f;
      c += __shfl_xor(c, 1, 64);
      c += __shfl_xor(c, 2, 64);
      c += __shfl_xor(c, 4, 64);
      c += __shfl_xor(c, 8, 64);
      c += __shfl_xor(c, 16, 64);
      c += __shfl_xor(c, 32, 64);
      a[d] += c;
    }
  }
  if (lane == 0) {
    for (int d = 0; d < NPB; ++d) {
      int node = node0 + d;
      if (node < n)
        out[node] = dinv[node] * (hws1[node] + a[d]) + bo[0];
    }
  }
}

// ---------------- launch ----------------

extern "C" void kernel_launch(void* const* d_in, const int* in_sizes, int n_in,
                              void* d_out, int out_size, void* d_ws, size_t ws_size,
                              hipStream_t stream) {
  const float* x   = (const float*)d_in[0];
  const int*   ei  = (const int*)d_in[1];
  const float* W_i = (const float*)d_in[2];
  const float* b_i = (const float*)d_in[3];
  const float* W_h = (const float*)d_in[4];
  const float* b_h = (const float*)d_in[5];
  const float* W_o = (const float*)d_in[6];
  const float* b_o = (const float*)d_in[7];

  const int N = in_sizes[0] / 64;   // 100000
  const int E = in_sizes[1] / 2;    // 2000000
  const int* srcArr = ei;           // edge_index[0]
  const int* dstArr = ei + E;       // edge_index[1]
  const int nbuck = (N + NPB - 1) >> BSH;   // 3125

  char* w = (char*)d_ws;
  auto take = [&](size_t bytes) -> char* {
    char* p = w;
    w += (bytes + 255) & ~(size_t)255;
    return p;
  };
  float* dinv      = (float*)take((size_t)N * 4);
  int*   bucketCnt = (int*)take((size_t)BMAX * 4);
  int*   bOff      = (int*)take((size_t)(BMAX + 1) * 4);
  int*   gCur      = (int*)take((size_t)BMAX * 4);
  int*   pairBuf   = (int*)take((size_t)E * 4);
  float* bufH      = (float*)take((size_t)N * 64 * 4);
  float* bufS      = (float*)take((size_t)N * 64 * 4);
  float* hws1      = (float*)take((size_t)N * 4);
  (void)ws_size; (void)n_in; (void)out_size;

  const int nbN    = (N + TPB - 1) / TPB;
  const int nbEd   = (E + EPB - 1) / EPB;
  const int nbGemm = (N + 63) / 64;

  // bucketing + dinv + src-sort (one-time)
  hipMemsetAsync(bucketCnt, 0, (size_t)BMAX * 4, stream);
  k_hist  <<<nbEd, TPB, 0, stream>>>(dstArr, bucketCnt, E, nbuck);
  k_bscan <<<1, 1024, 0, stream>>>(bucketCnt, bOff, gCur, nbuck);
  k_bucket<<<nbEd, TPB, 0, stream>>>(srcArr, dstArr, gCur, pairBuf, E, nbuck);
  k_deg   <<<nbuck, TPB, 0, stream>>>(pairBuf, bOff, dinv, N);
  k_sort  <<<nbuck, TPB, 0, stream>>>(pairBuf, bOff);

  // layer 0: x -> bufS -> bufH
  k_gemm<<<nbGemm, TPB, 0, stream>>>(x, W_i, dinv, bufS, 0, N);
  k_swp <<<nbuck, 64, 0, stream>>>(bufS, pairBuf, bOff, dinv, b_i, bufH, N);

  // 6 hidden layers
  for (int l = 0; l < 6; ++l) {
    k_gemm<<<nbGemm, TPB, 0, stream>>>(bufH, W_h + (size_t)l * 64 * 64, dinv, bufS, 1, N);
    k_swp <<<nbuck, 64, 0, stream>>>(bufS, pairBuf, bOff, dinv, b_h + (size_t)l * 64, bufH, N);
  }

  // output layer: 64 -> 1
  k_fdot<<<nbN, TPB, 0, stream>>>(bufH, W_o, dinv, hws1, N);
  k_fsc <<<nbuck, 64, 0, stream>>>(hws1, pairBuf, bOff, dinv, b_o, (float*)d_out, N);
}

// Round 13
// 713.120 us; speedup vs baseline: 1.5850x; 1.2021x over previous
//
#include <hip/hip_runtime.h>
#include <math.h>

#define TPB 256
#define BSH 8                  // 256 nodes per bucket (TPB must equal 1<<BSH)
#define BMAX 512               // max buckets (N <= 131072)
#define EPB 4096               // edges per block in hist/bucket passes

// ---------------- CSR build (bucketed, no global random atomics) ----------------

__global__ __launch_bounds__(TPB) void k_hist(const int* __restrict__ dst,
                                              int* __restrict__ bucketCnt,
                                              int nE, int nbuck) {
  __shared__ int h[BMAX];
  for (int i = threadIdx.x; i < BMAX; i += TPB) h[i] = 0;
  __syncthreads();
  int base = blockIdx.x * EPB;
  for (int i = threadIdx.x; i < EPB; i += TPB) {
    int e = base + i;
    if (e < nE) atomicAdd(&h[dst[e] >> BSH], 1);
  }
  __syncthreads();
  for (int i = threadIdx.x; i < nbuck; i += TPB)
    if (h[i]) atomicAdd(&bucketCnt[i], h[i]);
}

__global__ __launch_bounds__(BMAX) void k_bscan(const int* __restrict__ bucketCnt,
                                                int* __restrict__ bOff,
                                                int* __restrict__ gCur,
                                                int* __restrict__ rowPtr,
                                                int nbuck, int n, int nE) {
  __shared__ int sd[BMAX];
  int t = threadIdx.x;
  int v = (t < nbuck) ? bucketCnt[t] : 0;
  sd[t] = v;
  __syncthreads();
  for (int off = 1; off < BMAX; off <<= 1) {
    int add = (t >= off) ? sd[t - off] : 0;
    __syncthreads();
    sd[t] += add;
    __syncthreads();
  }
  if (t < nbuck) {
    bOff[t + 1] = sd[t];
    gCur[t] = sd[t] - v;     // exclusive prefix
  }
  if (t == 0) { bOff[0] = 0; rowPtr[n] = nE; }
}

__global__ __launch_bounds__(TPB) void k_bucket(const int* __restrict__ src,
                                                const int* __restrict__ dst,
                                                int* __restrict__ gCur,
                                                int* __restrict__ pairBuf,
                                                int nE, int nbuck) {
  __shared__ int   hist[BMAX];
  __shared__ int   baseL[BMAX];
  __shared__ int   sp[EPB];
  __shared__ short sbk[EPB];
  for (int i = threadIdx.x; i < BMAX; i += TPB) hist[i] = 0;
  __syncthreads();
  int cb = blockIdx.x * EPB;
  for (int i = threadIdx.x; i < EPB; i += TPB) {
    int e = cb + i;
    if (e < nE) {
      int s = src[e], d = dst[e];
      int b = d >> BSH;
      sp[i]  = s | ((d & ((1 << BSH) - 1)) << 20);
      sbk[i] = (short)b;
      atomicAdd(&hist[b], 1);
    } else sbk[i] = -1;
  }
  __syncthreads();
  for (int i = threadIdx.x; i < nbuck; i += TPB)
    baseL[i] = hist[i] ? atomicAdd(&gCur[i], hist[i]) : 0;
  __syncthreads();
  for (int i = threadIdx.x; i < BMAX; i += TPB) hist[i] = 0;  // reuse as cursor
  __syncthreads();
  for (int i = threadIdx.x; i < EPB; i += TPB) {
    int b = sbk[i];
    if (b >= 0) {
      int r = atomicAdd(&hist[b], 1);
      pairBuf[baseL[b] + r] = sp[i];
    }
  }
}

__global__ __launch_bounds__(TPB) void k_final(const int* __restrict__ pairBuf,
                                               const int* __restrict__ bOff,
                                               int* __restrict__ rowPtr,
                                               int* __restrict__ col,
                                               float* __restrict__ dinv,
                                               int n) {
  __shared__ int h[TPB];
  __shared__ int ex[TPB];
  int t = threadIdx.x;
  int b = blockIdx.x;
  int p0 = bOff[b], p1 = bOff[b + 1];
  h[t] = 0;
  __syncthreads();
  for (int i = p0 + t; i < p1; i += TPB)
    atomicAdd(&h[pairBuf[i] >> 20], 1);
  __syncthreads();
  int v = h[t];
  ex[t] = v;
  __syncthreads();
  for (int off = 1; off < TPB; off <<= 1) {
    int add = (t >= off) ? ex[t - off] : 0;
    __syncthreads();
    ex[t] += add;
    __syncthreads();
  }
  int excl = ex[t] - v;
  int node = (b << BSH) + t;
  if (node < n) {
    rowPtr[node] = p0 + excl;
    dinv[node]   = rsqrtf((float)(v + 1));  // +1 self loop
  }
  __syncthreads();
  h[t] = excl;  // reuse as per-local-node cursor
  __syncthreads();
  for (int i = p0 + t; i < p1; i += TPB) {
    int p = pairBuf[i];
    int r = atomicAdd(&h[p >> 20], 1);
    col[p0 + r] = p & 0xFFFFF;
  }
}

// ---------------- per-layer kernels ----------------

// HWS[n][c] = (act(H[n]) @ W)[c] * dinv[n]
__global__ __launch_bounds__(TPB, 4) void k_gemm(const float* __restrict__ H,
                                                 const float* __restrict__ W,
                                                 const float* __restrict__ dinv,
                                                 float* __restrict__ HWS,
                                                 int relu, int rows) {
  __shared__ float Wl[64 * 64];     // [k][c]
  __shared__ float Hl[64][68];      // [r][k], padded
  const int tid = threadIdx.x;
  const int c0 = (tid & 15) * 4;
  const int r0 = (tid >> 4) * 4;
  const int row0 = blockIdx.x * 64;

  for (int i = tid; i < 64 * 16; i += TPB)
    ((float4*)Wl)[i] = ((const float4*)W)[i];

  for (int i = tid; i < 64 * 16; i += TPB) {
    int r = i >> 4, q = i & 15;
    int gr = row0 + r;
    float4 v = make_float4(0.f, 0.f, 0.f, 0.f);
    if (gr < rows) v = ((const float4*)(H + (size_t)gr * 64))[q];
    if (relu) {
      v.x = fmaxf(v.x, 0.f); v.y = fmaxf(v.y, 0.f);
      v.z = fmaxf(v.z, 0.f); v.w = fmaxf(v.w, 0.f);
    }
    *(float4*)&Hl[r][q * 4] = v;
  }
  __syncthreads();

  float acc[4][4] = {{0.f,0.f,0.f,0.f},{0.f,0.f,0.f,0.f},
                     {0.f,0.f,0.f,0.f},{0.f,0.f,0.f,0.f}};
#pragma unroll 4
  for (int k = 0; k < 64; ++k) {
    float4 w = *(const float4*)&Wl[k * 64 + c0];
    float h0 = Hl[r0 + 0][k];
    float h1 = Hl[r0 + 1][k];
    float h2 = Hl[r0 + 2][k];
    float h3 = Hl[r0 + 3][k];
    acc[0][0] = fmaf(h0, w.x, acc[0][0]); acc[0][1] = fmaf(h0, w.y, acc[0][1]);
    acc[0][2] = fmaf(h0, w.z, acc[0][2]); acc[0][3] = fmaf(h0, w.w, acc[0][3]);
    acc[1][0] = fmaf(h1, w.x, acc[1][0]); acc[1][1] = fmaf(h1, w.y, acc[1][1]);
    acc[1][2] = fmaf(h1, w.z, acc[1][2]); acc[1][3] = fmaf(h1, w.w, acc[1][3]);
    acc[2][0] = fmaf(h2, w.x, acc[2][0]); acc[2][1] = fmaf(h2, w.y, acc[2][1]);
    acc[2][2] = fmaf(h2, w.z, acc[2][2]); acc[2][3] = fmaf(h2, w.w, acc[2][3]);
    acc[3][0] = fmaf(h3, w.x, acc[3][0]); acc[3][1] = fmaf(h3, w.y, acc[3][1]);
    acc[3][2] = fmaf(h3, w.z, acc[3][2]); acc[3][3] = fmaf(h3, w.w, acc[3][3]);
  }

#pragma unroll
  for (int i = 0; i < 4; ++i) {
    int gr = row0 + r0 + i;
    if (gr < rows) {
      float s = dinv[gr];
      float4 o = make_float4(acc[i][0] * s, acc[i][1] * s,
                             acc[i][2] * s, acc[i][3] * s);
      *(float4*)&HWS[(size_t)gr * 64 + c0] = o;
    }
  }
}

// OUT[n][c] = dinv[n] * (HWS[n][c] + sum_{e in row n} HWS[col[e]][c]) + bias[c]
// Wave per node. lane = (edge-slot eg = lane>>4, channel-quad q = lane&15).
// One dwordx4 load gathers 4 full 256B rows (1KB) per instruction.
// NOTE: every __shfl sits in wave-uniform control flow (CDNA ds_bpermute
// returns UNDEFINED data when the source lane is exec-inactive — round-4 bug).
__global__ __launch_bounds__(TPB) void k_scatter(const float* __restrict__ HWS,
                                                 const int* __restrict__ rowPtr,
                                                 const int* __restrict__ col,
                                                 const float* __restrict__ dinv,
                                                 const float* __restrict__ bias,
                                                 float* __restrict__ OUT, int n) {
  int wave = blockIdx.x * (TPB / 64) + (threadIdx.x >> 6);
  if (wave >= n) return;
  const int lane = threadIdx.x & 63;
  const int eg = lane >> 4;   // edge slot 0..3
  const int q  = lane & 15;   // channel quad
  const int node = wave;

  float4 acc = make_float4(0.f, 0.f, 0.f, 0.f);
  if (eg == 0)  // self loop counted once
    acc = *(const float4*)&HWS[(size_t)node * 64 + q * 4];

  const int e0 = rowPtr[node];
  const int deg = rowPtr[node + 1] - e0;

  for (int base = 0; base < deg; base += 64) {
    int m = deg - base; if (m > 64) m = 64;
    int idxv = (lane < m) ? col[e0 + base + lane] : 0;
    int j = 0;
    // uniform trip counts: all 64 lanes active at every __shfl below
    for (; j + 16 <= m; j += 16) {
      int s0 = __shfl(idxv, j + eg,      64);
      int s1 = __shfl(idxv, j + 4 + eg,  64);
      int s2 = __shfl(idxv, j + 8 + eg,  64);
      int s3 = __shfl(idxv, j + 12 + eg, 64);
      float4 v0 = *(const float4*)&HWS[(size_t)s0 * 64 + q * 4];
      float4 v1 = *(const float4*)&HWS[(size_t)s1 * 64 + q * 4];
      float4 v2 = *(const float4*)&HWS[(size_t)s2 * 64 + q * 4];
      float4 v3 = *(const float4*)&HWS[(size_t)s3 * 64 + q * 4];
      acc.x += (v0.x + v1.x) + (v2.x + v3.x);
      acc.y += (v0.y + v1.y) + (v2.y + v3.y);
      acc.z += (v0.z + v1.z) + (v2.z + v3.z);
      acc.w += (v0.w + v1.w) + (v2.w + v3.w);
    }
    for (; j + 8 <= m; j += 8) {
      int s0 = __shfl(idxv, j + eg,     64);
      int s1 = __shfl(idxv, j + 4 + eg, 64);
      float4 v0 = *(const float4*)&HWS[(size_t)s0 * 64 + q * 4];
      float4 v1 = *(const float4*)&HWS[(size_t)s1 * 64 + q * 4];
      acc.x += v0.x + v1.x;
      acc.y += v0.y + v1.y;
      acc.z += v0.z + v1.z;
      acc.w += v0.w + v1.w;
    }
    for (; j < m; j += 4) {
      int jj = j + eg;
      int jc = (jj < m) ? jj : (m - 1);     // clamp: source lane always < m
      int s = __shfl(idxv, jc, 64);         // executed by ALL lanes (uniform)
      if (jj < m) {                         // only the gather is predicated
        float4 v = *(const float4*)&HWS[(size_t)s * 64 + q * 4];
        acc.x += v.x; acc.y += v.y; acc.z += v.z; acc.w += v.w;
      }
    }
  }

  // reduce across the 4 edge slots (lanes q, q+16, q+32, q+48)
#pragma unroll
  for (int off = 16; off < 64; off <<= 1) {
    acc.x += __shfl_xor(acc.x, off, 64);
    acc.y += __shfl_xor(acc.y, off, 64);
    acc.z += __shfl_xor(acc.z, off, 64);
    acc.w += __shfl_xor(acc.w, off, 64);
  }

  if (eg == 0) {
    float s = dinv[node];
    float4 b4 = *(const float4*)&bias[q * 4];
    float4 o = make_float4(acc.x * s + b4.x, acc.y * s + b4.y,
                           acc.z * s + b4.z, acc.w * s + b4.w);
    *(float4*)&OUT[(size_t)node * 64 + q * 4] = o;
  }
}

// hws1[n] = (relu(H[n]) . Wo) * dinv[n]
__global__ __launch_bounds__(TPB) void k_fdot(const float* __restrict__ H,
                                              const float* __restrict__ Wo,
                                              const float* __restrict__ dinv,
                                              float* __restrict__ hws1, int n) {
  int i = blockIdx.x * TPB + threadIdx.x;
  if (i >= n) return;
  const float4* Hv = (const float4*)(H + (size_t)i * 64);
  float acc = 0.f;
#pragma unroll
  for (int q = 0; q < 16; ++q) {
    float4 v = Hv[q];
    acc += fmaxf(v.x, 0.f) * Wo[4 * q + 0];
    acc += fmaxf(v.y, 0.f) * Wo[4 * q + 1];
    acc += fmaxf(v.z, 0.f) * Wo[4 * q + 2];
    acc += fmaxf(v.w, 0.f) * Wo[4 * q + 3];
  }
  hws1[i] = acc * dinv[i];
}

__global__ __launch_bounds__(TPB) void k_fscat(const float* __restrict__ hws1,
                                               const int* __restrict__ rowPtr,
                                               const int* __restrict__ col,
                                               const float* __restrict__ dinv,
                                               const float* __restrict__ bo,
                                               float* __restrict__ out, int n) {
  int i = blockIdx.x * TPB + threadIdx.x;
  if (i >= n) return;
  float a0 = hws1[i], a1 = 0.f, a2 = 0.f, a3 = 0.f;
  int e0 = rowPtr[i], e1 = rowPtr[i + 1];
  int e = e0;
  for (; e + 4 <= e1; e += 4) {
    a0 += hws1[col[e]];
    a1 += hws1[col[e + 1]];
    a2 += hws1[col[e + 2]];
    a3 += hws1[col[e + 3]];
  }
  for (; e < e1; ++e) a0 += hws1[col[e]];
  out[i] = dinv[i] * ((a0 + a1) + (a2 + a3)) + bo[0];
}

// ---------------- launch ----------------

extern "C" void kernel_launch(void* const* d_in, const int* in_sizes, int n_in,
                              void* d_out, int out_size, void* d_ws, size_t ws_size,
                              hipStream_t stream) {
  const float* x   = (const float*)d_in[0];
  const int*   ei  = (const int*)d_in[1];
  const float* W_i = (const float*)d_in[2];
  const float* b_i = (const float*)d_in[3];
  const float* W_h = (const float*)d_in[4];
  const float* b_h = (const float*)d_in[5];
  const float* W_o = (const float*)d_in[6];
  const float* b_o = (const float*)d_in[7];

  const int N = in_sizes[0] / 64;   // 100000
  const int E = in_sizes[1] / 2;    // 2000000
  const int* srcArr = ei;           // edge_index[0]
  const int* dstArr = ei + E;       // edge_index[1]
  const int nbuck = (N + (1 << BSH) - 1) >> BSH;   // 391

  char* w = (char*)d_ws;
  auto take = [&](size_t bytes) -> char* {
    char* p = w;
    w += (bytes + 255) & ~(size_t)255;
    return p;
  };
  int*   rowPtr    = (int*)take((size_t)(N + 1) * 4);
  int*   col       = (int*)take((size_t)E * 4);
  float* dinv      = (float*)take((size_t)N * 4);
  int*   bucketCnt = (int*)take((size_t)BMAX * 4);
  int*   bOff      = (int*)take((size_t)(BMAX + 1) * 4);
  int*   gCur      = (int*)take((size_t)BMAX * 4);
  float* bufH      = (float*)take((size_t)N * 64 * 4);
  float* bufS      = (float*)take((size_t)N * 64 * 4);
  float* hws1      = (float*)take((size_t)N * 4);
  int*   pairBuf   = (int*)bufS;   // alias: bufS unused during CSR build
  (void)ws_size; (void)n_in; (void)out_size;

  const int nbN    = (N + TPB - 1) / TPB;
  const int nbEd   = (E + EPB - 1) / EPB;
  const int nbGemm = (N + 63) / 64;
  const int nbScat = (N + 3) / 4;  // 4 waves per block

  // CSR build + dinv
  hipMemsetAsync(bucketCnt, 0, (size_t)BMAX * 4, stream);
  k_hist  <<<nbEd, TPB, 0, stream>>>(dstArr, bucketCnt, E, nbuck);
  k_bscan <<<1, BMAX, 0, stream>>>(bucketCnt, bOff, gCur, rowPtr, nbuck, N, E);
  k_bucket<<<nbEd, TPB, 0, stream>>>(srcArr, dstArr, gCur, pairBuf, E, nbuck);
  k_final <<<nbuck, TPB, 0, stream>>>(pairBuf, bOff, rowPtr, col, dinv, N);

  // layer 0: x -> bufS -> bufH
  k_gemm   <<<nbGemm, TPB, 0, stream>>>(x, W_i, dinv, bufS, 0, N);
  k_scatter<<<nbScat, TPB, 0, stream>>>(bufS, rowPtr, col, dinv, b_i, bufH, N);

  // 6 hidden layers
  for (int l = 0; l < 6; ++l) {
    k_gemm   <<<nbGemm, TPB, 0, stream>>>(bufH, W_h + (size_t)l * 64 * 64, dinv, bufS, 1, N);
    k_scatter<<<nbScat, TPB, 0, stream>>>(bufS, rowPtr, col, dinv, b_h + (size_t)l * 64, bufH, N);
  }

  // output layer: 64 -> 1
  k_fdot <<<nbN, TPB, 0, stream>>>(bufH, W_o, dinv, hws1, N);
  k_fscat<<<nbN, TPB, 0, stream>>>(hws1, rowPtr, col, dinv, b_o, (float*)d_out, N);
}